// Round 8
// baseline (108.783 us; speedup 1.0000x reference)
//
#include <hip/hip_runtime.h>

// B=16384, DIM=64, 8 coupling steps, H=8, D2=32.
// y = J^{-1} g applied analytically (triangular coupling blocks -> MLP JVPs);
// intermediate states recovered by inverting the flow from z = phi(x).
//
// R18: TLP attack. R10-R17 invariant: dur 38-43 us across unroll/roll,
// scratch removal, 1->2 waves/SIMD; each wave ~80% stalled, SIMD ~60%
// no-issue. The serial chain arithmetic is ~5 us; the gap is un-hidden
// latency at 2 waves/SIMD. Two changes buy 4 waves/SIMD:
//  (a) sHC H-cache REMOVED (-32 KiB LDS): in bwd, pair p's input state is
//      available before inversion (it's the state p didn't modify), so
//      H1/H2 are recomputed with the same L1/L2 MFMAs (+2 MFMA, +16 trans
//      per bwd half-step -- cheap at 7% MfmaUtil). Also kills the 1.15M
//      LDS bank conflicts (sHC was the only conflicting access).
//  (b) E=4 element mirror (lanes with equal n&3 are replicas; MFMA columns
//      are independent) -> 4096 waves; 512-thread blocks (8 waves, 32 elem),
//      grid 512, LDS 42 KiB -> 2 blocks/CU = 16 waves/CU = 4 waves/SIMD,
//      VGPR-capped 128 via waves_per_eu(4) (R17: natural usage is 128).
// Layout identity (gfx950, verified m89): D (col=lane&15,row=4q+reg) ==
// B-operand (n=lane&15,k=4q+j) for K=16 -> tanh(D)->pack is per-lane, zero
// cross-lane ops.

namespace {

typedef __fp16 f16x2 __attribute__((ext_vector_type(2)));
typedef __fp16 v4h __attribute__((ext_vector_type(4)));
typedef __fp16 v8h __attribute__((ext_vector_type(8)));
typedef float f32x4 __attribute__((ext_vector_type(4)));
typedef unsigned int u32;
typedef u32 u32x2 __attribute__((ext_vector_type(2)));
typedef u32 u32x4 __attribute__((ext_vector_type(4)));

constexpr int NB = 16384;

__device__ __forceinline__ float frcp(float x) { return __builtin_amdgcn_rcpf(x); }
__device__ __forceinline__ float ftanh(float x) {
  float e = __expf(2.f * x);
  return 1.f - 2.f * frcp(e + 1.f);
}
__device__ __forceinline__ f16x2 pk(float a, float b) {
  return __builtin_amdgcn_cvt_pkrtz(a, b);
}
// Pure-SSA operand assembly: initializer-list vectors + bitcast, no memory.
__device__ __forceinline__ v8h mk8(f16x2 a, f16x2 b, f16x2 c, f16x2 d) {
  const u32x4 t = {__builtin_bit_cast(u32, a), __builtin_bit_cast(u32, b),
                   __builtin_bit_cast(u32, c), __builtin_bit_cast(u32, d)};
  return __builtin_bit_cast(v8h, t);
}
__device__ __forceinline__ v4h mk4(f16x2 a, f16x2 b) {
  const u32x2 t = {__builtin_bit_cast(u32, a), __builtin_bit_cast(u32, b)};
  return __builtin_bit_cast(v4h, t);
}

// net pair p (0..15): step i = p>>1, half = p&1 -> t-net base.
__device__ __forceinline__ int pbase(int p) {
  return ((p >> 1) << 2) + ((p & 1) << 1);
}

}  // namespace

// ---- forward L3 block: one output quad -> four named scalars ----
#define L3_FWD(P, BB, D0, D1, D2, D3)                                         \
  do {                                                                        \
    const bool act_ = ((BB) < 2) == (q < 2);                                  \
    v4h Ab = *(const v4h*)(LW2 + ((P)*256 + (BB)*64 + abbase));               \
    Ab = act_ ? Ab : z4;                                                      \
    const f32x4 cb = *(const f32x4*)(LB2 + ((P)*4 + (BB)) * 16 + q * 4);      \
    const f32x4 ob =                                                          \
        __builtin_amdgcn_mfma_f32_16x16x16f16(Ab, H2v, cb, 0, 0, 0);          \
    D0 = ob[0]; D1 = ob[1]; D2 = ob[2]; D3 = ob[3];                           \
  } while (0)

#define FWD_UPD(J, W) W##J = fmaf(W##J, __expf(s##J), t##J)

// ---- forward half-step P: reads V0..V7 (prefix V), updates W0..W7 ----
#define FWD_HALF(P, V, W)                                                     \
  do {                                                                        \
    const v8h Bq = mk8(pk(V##0, V##1), pk(V##2, V##3), pk(V##4, V##5),        \
                       pk(V##6, V##7));                                       \
    const v8h A0 = *(const v8h*)(LW0 + (((P)*64 + q * 16 + n) << 2));         \
    const f32x4 c0 = *(const f32x4*)(LB0 + (P)*16 + q * 4);                   \
    f32x4 d1 = __builtin_amdgcn_mfma_f32_16x16x32_f16(A0, Bq, c0, 0, 0, 0);   \
    const f16x2 H1a = pk(ftanh(d1[0]), ftanh(d1[1]));                         \
    const f16x2 H1b = pk(ftanh(d1[2]), ftanh(d1[3]));                         \
    v4h A1 = *(const v4h*)(LW1 + ((P)*64 + a1off));                           \
    A1 = act1 ? A1 : z4;                                                      \
    const f32x4 c1 = *(const f32x4*)(LB1 + (P)*16 + q * 4);                   \
    f32x4 d2 =                                                                \
        __builtin_amdgcn_mfma_f32_16x16x16f16(A1, mk4(H1a, H1b), c1, 0, 0, 0);\
    const f16x2 H2a = pk(ftanh(d2[0]), ftanh(d2[1]));                         \
    const f16x2 H2b = pk(ftanh(d2[2]), ftanh(d2[3]));                         \
    const v4h H2v = mk4(H2a, H2b);                                            \
    float t0, t1, t2, t3, t4, t5, t6, t7;                                     \
    float s0, s1, s2, s3, s4, s5, s6, s7;                                     \
    L3_FWD(P, 0, t0, t1, t2, t3);                                             \
    L3_FWD(P, 1, t4, t5, t6, t7);                                             \
    L3_FWD(P, 2, s0, s1, s2, s3);                                             \
    L3_FWD(P, 3, s4, s5, s6, s7);                                             \
    FWD_UPD(0, W); FWD_UPD(1, W); FWD_UPD(2, W); FWD_UPD(3, W);               \
    FWD_UPD(4, W); FWD_UPD(5, W); FWD_UPD(6, W); FWD_UPD(7, W);               \
  } while (0)

// ---- backward L3 block: t/s recompute + JVP -> eight named scalars ----
#define L3_BWD(P, BB, D0, D1, D2, D3, J0, J1, J2, J3)                         \
  do {                                                                        \
    const bool act_ = ((BB) < 2) == (q < 2);                                  \
    v4h Ab = *(const v4h*)(LW2 + ((P)*256 + (BB)*64 + abbase));               \
    Ab = act_ ? Ab : z4;                                                      \
    const f32x4 cb = *(const f32x4*)(LB2 + ((P)*4 + (BB)) * 16 + q * 4);      \
    const f32x4 ob =                                                          \
        __builtin_amdgcn_mfma_f32_16x16x16f16(Ab, H2v, cb, 0, 0, 0);          \
    const f32x4 jb =                                                          \
        __builtin_amdgcn_mfma_f32_16x16x16f16(Ab, G2v, zc, 0, 0, 0);          \
    D0 = ob[0]; D1 = ob[1]; D2 = ob[2]; D3 = ob[3];                           \
    J0 = jb[0]; J1 = jb[1]; J2 = jb[2]; J3 = jb[3];                           \
  } while (0)

#define BWD_INV(J, ST, DME)                                                   \
  do {                                                                        \
    const float esi_ = __expf(-s##J);                                         \
    const float dd_ = ST##J - t##J;                                           \
    ST##J = dd_ * esi_;                                                       \
    DME##J = (DME##J - ut##J - dd_ * us##J) * esi_;                           \
  } while (0)

// ---- backward half-step P: inverts ST0..7, updates duals DME0..7; JVP at
// DOT0..7; H1/H2 RECOMPUTED from the pair's input state VIN0..7 ----
#define BWD_HALF(P, ST, DME, DOT, VIN)                                        \
  do {                                                                        \
    const v8h Bv = mk8(pk(VIN##0, VIN##1), pk(VIN##2, VIN##3),                \
                       pk(VIN##4, VIN##5), pk(VIN##6, VIN##7));               \
    const v8h Bu = mk8(pk(DOT##0, DOT##1), pk(DOT##2, DOT##3),                \
                       pk(DOT##4, DOT##5), pk(DOT##6, DOT##7));               \
    const v8h A0 = *(const v8h*)(LW0 + (((P)*64 + q * 16 + n) << 2));         \
    const f32x4 c0 = *(const f32x4*)(LB0 + (P)*16 + q * 4);                   \
    f32x4 d1 = __builtin_amdgcn_mfma_f32_16x16x32_f16(A0, Bv, c0, 0, 0, 0);   \
    f32x4 d1u = __builtin_amdgcn_mfma_f32_16x16x32_f16(A0, Bu, zc, 0, 0, 0);  \
    const float h10 = ftanh(d1[0]), h11 = ftanh(d1[1]);                       \
    const float h12 = ftanh(d1[2]), h13 = ftanh(d1[3]);                       \
    const f16x2 H1a = pk(h10, h11);                                           \
    const f16x2 H1b = pk(h12, h13);                                           \
    const f16x2 G1a =                                                         \
        pk((1.f - h10 * h10) * d1u[0], (1.f - h11 * h11) * d1u[1]);           \
    const f16x2 G1b =                                                         \
        pk((1.f - h12 * h12) * d1u[2], (1.f - h13 * h13) * d1u[3]);           \
    v4h A1 = *(const v4h*)(LW1 + ((P)*64 + a1off));                           \
    A1 = act1 ? A1 : z4;                                                      \
    const f32x4 c1 = *(const f32x4*)(LB1 + (P)*16 + q * 4);                   \
    f32x4 d2 =                                                                \
        __builtin_amdgcn_mfma_f32_16x16x16f16(A1, mk4(H1a, H1b), c1, 0, 0, 0);\
    f32x4 d2u =                                                               \
        __builtin_amdgcn_mfma_f32_16x16x16f16(A1, mk4(G1a, G1b), zc, 0, 0, 0);\
    const float h20 = ftanh(d2[0]), h21 = ftanh(d2[1]);                       \
    const float h22 = ftanh(d2[2]), h23 = ftanh(d2[3]);                       \
    const f16x2 G2a =                                                         \
        pk((1.f - h20 * h20) * d2u[0], (1.f - h21 * h21) * d2u[1]);           \
    const f16x2 G2b =                                                         \
        pk((1.f - h22 * h22) * d2u[2], (1.f - h23 * h23) * d2u[3]);           \
    const v4h H2v = mk4(pk(h20, h21), pk(h22, h23));                          \
    const v4h G2v = mk4(G2a, G2b);                                            \
    float t0, t1, t2, t3, t4, t5, t6, t7;                                     \
    float s0, s1, s2, s3, s4, s5, s6, s7;                                     \
    float ut0, ut1, ut2, ut3, ut4, ut5, ut6, ut7;                             \
    float us0, us1, us2, us3, us4, us5, us6, us7;                             \
    L3_BWD(P, 0, t0, t1, t2, t3, ut0, ut1, ut2, ut3);                         \
    L3_BWD(P, 1, t4, t5, t6, t7, ut4, ut5, ut6, ut7);                         \
    L3_BWD(P, 2, s0, s1, s2, s3, us0, us1, us2, us3);                         \
    L3_BWD(P, 3, s4, s5, s6, s7, us4, us5, us6, us7);                         \
    BWD_INV(0, ST, DME); BWD_INV(1, ST, DME);                                 \
    BWD_INV(2, ST, DME); BWD_INV(3, ST, DME);                                 \
    BWD_INV(4, ST, DME); BWD_INV(5, ST, DME);                                 \
    BWD_INV(6, ST, DME); BWD_INV(7, ST, DME);                                 \
  } while (0)

// 512 threads = 8 waves = 32 elements/block (4/wave, mirrored), grid 512 ->
// 4096 waves. LDS = 42 KiB weights only -> 2 blocks/CU co-resident ->
// 16 waves/CU = 4 waves/SIMD (VGPR 128 cap via waves_per_eu(4)).
__global__ __attribute__((amdgpu_flat_work_group_size(512, 512),
                          amdgpu_waves_per_eu(4, 8))) void nf_policy_kernel(
    const float* __restrict__ x, const float* __restrict__ xs,
    const float* __restrict__ gW0, const float* __restrict__ gb0,
    const float* __restrict__ gW1, const float* __restrict__ gb1,
    const float* __restrict__ gW2, const float* __restrict__ gb2,
    float* __restrict__ out) {
  __shared__ __align__(16) f16x2 LW0[4096];  // [16p][4q][16m][4w] A-frags L1
  __shared__ __align__(16) f16x2 LW1[1024];  // [16p][2half][8row][4kk]
  __shared__ __align__(16) f16x2 LW2[4096];  // [16p][4b][16m][4kk(2 used)]
  __shared__ __align__(16) float LB0[256];   // [16p][16m]
  __shared__ __align__(16) float LB1[256];   // [16p][16m]
  __shared__ __align__(16) float LB2[1024];  // [16p][4b][16m]

  const int tid = threadIdx.x;
  // ---- stage weights: fp32 global -> f16 LDS in MFMA A-fragment order ----
  for (int i = tid; i < 4096; i += 512) {  // LW0
    const int p = i >> 8, rem = i & 255, qq = rem >> 6, rem2 = rem & 63;
    const int mm = rem2 >> 2, w = rem2 & 3;
    const int net = pbase(p) + (mm >> 3);
    const int h = mm & 7, k0 = qq * 8 + w * 2;
    const float* src = gW0 + net * 256 + h * 32 + k0;
    LW0[i] = pk(src[0], src[1]);
  }
  for (int i = tid; i < 1024; i += 512) {  // LW1
    const int p = i >> 6, rem = i & 63, half = rem >> 5;
    const int row = (rem >> 2) & 7, kk = rem & 3;
    const int net = pbase(p) + half;
    const float* src = gW1 + net * 64 + row * 8 + kk * 2;
    LW1[i] = pk(src[0], src[1]);
  }
  for (int i = tid; i < 4096; i += 512) {  // LW2 (rows permuted)
    const int p = i >> 8, rem = i & 255, b = rem >> 6, rem2 = rem & 63;
    const int mm = rem2 >> 2, kk = rem2 & 3;
    const int net = pbase(p) + (b >> 1);
    const int d = 8 * (mm >> 2) + ((b & 1) << 2) + (mm & 3);
    const float* src = gW2 + net * 256 + d * 8 + kk * 2;
    LW2[i] = pk(src[0], src[1]);
  }
  for (int i = tid; i < 256; i += 512) {  // LB0/LB1
    const int p = i >> 4, mm = i & 15;
    const int net = pbase(p) + (mm >> 3);
    LB0[i] = gb0[net * 8 + (mm & 7)];
    LB1[i] = gb1[net * 8 + (mm & 7)];
  }
  for (int i = tid; i < 1024; i += 512) {  // LB2 (permuted like LW2 rows)
    const int p = i >> 6, b = (i >> 4) & 3, mm = i & 15;
    const int net = pbase(p) + (b >> 1);
    const int d = 8 * (mm >> 2) + ((b & 1) << 2) + (mm & 3);
    LB2[i] = gb2[net * 32 + d];
  }
  __syncthreads();

  const int lane = tid & 63;
  const int wv = tid >> 6;
  const int n = lane & 15;   // MFMA col / A row role (lanes n>=4 mirror n&3)
  const int q = lane >> 4;   // quad: owns state dims 8q..8q+7
  const int e = blockIdx.x * 32 + wv * 4 + (n & 3);

  const v4h z4 = {(__fp16)0.f, (__fp16)0.f, (__fp16)0.f, (__fp16)0.f};
  const f32x4 zc = {0.f, 0.f, 0.f, 0.f};
  const bool act1 = (n < 8) == (q < 2);
  const int a1off = ((n & 7) << 2) + ((q & 1) << 1) + ((n >= 8) ? 32 : 0);
  const int abbase = n * 4 + ((q & 1) << 1);

  float lo0, lo1, lo2, lo3, lo4, lo5, lo6, lo7;
  float up0, up1, up2, up3, up4, up5, up6, up7;
  float av0, av1, av2, av3, av4, av5, av6, av7;
  float bv0, bv1, bv2, bv3, bv4, bv5, bv6, bv7;
  {
    const float* xe = x + (size_t)e * 64;
    const float* se = xs + (size_t)e * 64;
    const float4 a0 = *(const float4*)(xe + q * 8);
    const float4 a1 = *(const float4*)(xe + q * 8 + 4);
    const float4 u0 = *(const float4*)(xe + 32 + q * 8);
    const float4 u1 = *(const float4*)(xe + 32 + q * 8 + 4);
    const float4 p0 = *(const float4*)(se + q * 8);
    const float4 p1 = *(const float4*)(se + q * 8 + 4);
    const float4 r0 = *(const float4*)(se + 32 + q * 8);
    const float4 r1 = *(const float4*)(se + 32 + q * 8 + 4);
    lo0 = a0.x; lo1 = a0.y; lo2 = a0.z; lo3 = a0.w;
    lo4 = a1.x; lo5 = a1.y; lo6 = a1.z; lo7 = a1.w;
    up0 = u0.x; up1 = u0.y; up2 = u0.z; up3 = u0.w;
    up4 = u1.x; up5 = u1.y; up6 = u1.z; up7 = u1.w;
    av0 = -2.f * (a0.x - p0.x); av1 = -2.f * (a0.y - p0.y);
    av2 = -2.f * (a0.z - p0.z); av3 = -2.f * (a0.w - p0.w);
    av4 = -2.f * (a1.x - p1.x); av5 = -2.f * (a1.y - p1.y);
    av6 = -2.f * (a1.z - p1.z); av7 = -2.f * (a1.w - p1.w);
    bv0 = -2.f * (u0.x - r0.x); bv1 = -2.f * (u0.y - r0.y);
    bv2 = -2.f * (u0.z - r0.z); bv3 = -2.f * (u0.w - r0.w);
    bv4 = -2.f * (u1.x - r1.x); bv5 = -2.f * (u1.y - r1.y);
    bv6 = -2.f * (u1.z - r1.z); bv7 = -2.f * (u1.w - r1.w);
  }

  // ---------------- forward: z = phi(x) ---------------
  // even p: reads lo, updates up; odd p: reads up, updates lo.
#pragma clang loop unroll(disable)
  for (int st = 0; st < 8; ++st) {
    const int p0i = 2 * st;
    FWD_HALF(p0i, lo, up);
    FWD_HALF(p0i + 1, up, lo);
  }

  // ------------- backward: y = J^{-1} g, inverting the flow -------------
  // odd p first: inverts lo (input up, dual-in bv, dual-out av);
  // then even p: inverts up (input lo just reconstructed).
#pragma clang loop unroll(disable)
  for (int st = 7; st >= 0; --st) {
    const int p0i = 2 * st;
    BWD_HALF(p0i + 1, lo, av, bv, up);
    BWD_HALF(p0i, up, bv, av, lo);
  }

  if (n < 4) {
    float* oe = out + (size_t)e * 64;
    float4 v;
    v.x = av0; v.y = av1; v.z = av2; v.w = av3;
    *(float4*)(oe + q * 8) = v;
    v.x = av4; v.y = av5; v.z = av6; v.w = av7;
    *(float4*)(oe + q * 8 + 4) = v;
    v.x = bv0; v.y = bv1; v.z = bv2; v.w = bv3;
    *(float4*)(oe + 32 + q * 8) = v;
    v.x = bv4; v.y = bv5; v.z = bv6; v.w = bv7;
    *(float4*)(oe + 32 + q * 8 + 4) = v;
  }
}

extern "C" void kernel_launch(void* const* d_in, const int* in_sizes, int n_in,
                              void* d_out, int out_size, void* d_ws,
                              size_t ws_size, hipStream_t stream) {
  const float* x  = (const float*)d_in[0];
  const float* xs = (const float*)d_in[1];
  const float* W0 = (const float*)d_in[2];
  const float* b0 = (const float*)d_in[3];
  const float* W1 = (const float*)d_in[4];
  const float* b1 = (const float*)d_in[5];
  const float* W2 = (const float*)d_in[6];
  const float* b2 = (const float*)d_in[7];
  float* out = (float*)d_out;

  dim3 grid(NB / 32);  // 512 blocks, 32 elements each (4 per wave, mirrored)
  dim3 block(512);
  nf_policy_kernel<<<grid, block, 0, stream>>>(x, xs, W0, b0, W1, b1, W2, b2,
                                               out);
}